// Round 3
// baseline (90.113 us; speedup 1.0000x reference)
//
#include <hip/hip_runtime.h>

// Hausdorff adv2ori via MFMA: B=8, K=8192.
// dist(n,m) = oo_n + aa_m - 2*o.a ; C = mfma(A',B') = oo_n - 2*o.a (fp16 hi/lo split)
// loss = mean_b( w_b * max_m min_n dist )
//
// K=16 slot packing (one 32x32x16_f16 MFMA per 32x32 pair tile):
//   A'(ori n): [oh.x oh.y oh.z | oh.x oh.y oh.z | ol.x ol.y ol.z | oo_h oo_l | 0 x5]
//   B'(adv m): [bh.x bh.y bh.z | bl.x bl.y bl.z | bh.x bh.y bh.z | 1    1    | 0 x5]
//   b = -2*a; dropped ol.bl terms ~1e-6; fp32 accumulate. absmax=0 in R1/R2.
//
// R2 post-mortem: per-iteration timing includes a fixed ~40us harness workspace
// re-poison fill (268MB) we cannot remove. Our controllable time ~46us:
// hausdorff ~30-35 (staging latency barrier-exposed) + memset + reduceB + gaps.
// R3: double-buffered LDS staging w/ register prefetch (latency hidden under
// MFMAs), plain-store partial mins part[ns][b][col] (no init -> memset dispatch
// deleted, no atomicMin), reduceB atomicAdds weighted term into out (zeroed by
// K1). Two dispatches total.

#define KPTS 8192
#define BATCH 8

#define CBLK 256              // adv columns per block (4 waves x 64)
#define NSPLIT 8              // row splits, combined via plain-store partials
#define RBLK (KPTS / NSPLIT)  // 1024 ori rows per block
#define CHUNK 256             // rows per LDS buffer (8 KB; x2 double-buffered)
#define NCHUNK (RBLK / CHUNK) // 4
#define CTILES (CHUNK / 32)   // 8 MFMA row-tiles per chunk

typedef _Float16 half8 __attribute__((ext_vector_type(8)));
typedef float f32x16 __attribute__((ext_vector_type(16)));

// min of 16 fp32 (fuses to v_min3 tree)
__device__ __forceinline__ float min16(const f32x16 c) {
    float u0 = fminf(fminf(c[0],  c[1]),  c[2]);
    float u1 = fminf(fminf(c[3],  c[4]),  c[5]);
    float u2 = fminf(fminf(c[6],  c[7]),  c[8]);
    float u3 = fminf(fminf(c[9],  c[10]), c[11]);
    float u4 = fminf(fminf(c[12], c[13]), c[14]);
    float u5 = fminf(fminf(u0, u1), c[15]);
    float u6 = fminf(fminf(u2, u3), u4);
    return fminf(u5, u6);
}

__global__ __launch_bounds__(256) void hausdorff(const float* __restrict__ adv,
                                                 const float* __restrict__ ori,
                                                 float* __restrict__ part,
                                                 float* __restrict__ out) {
    __shared__ _Float16 sA[2][CHUNK * 16];   // 2 x 8 KB A'-chunks

    const int bid  = blockIdx.x;             // grid = 8 * 32 * 8 = 2048
    const int b    = bid >> 8;
    const int mc   = (bid >> 3) & 31;        // column chunk (256 cols)
    const int ns   = bid & 7;                // row split
    const int tid  = threadIdx.x;
    const int lane = tid & 63;
    const int wv   = tid >> 6;
    const int r    = lane & 31;              // MFMA row/col index
    const int hk   = lane >> 5;              // K-half

    if (bid == 0 && tid == 0) out[0] = 0.0f; // for reduceB's atomicAdd

    const _Float16 Z = (_Float16)0.0f, ONE = (_Float16)1.0f;

    // ---- B-fragments + aa from adv (once per block, registers) ----
    const float* advb = adv + (size_t)b * KPTS * 3;
    const int m0 = mc * CBLK + wv * 64 + r;
    const int m1 = m0 + 32;
    half8 bf0, bf1;
    float aa0, aa1;
    {
        float ax = advb[3 * m0], ay = advb[3 * m0 + 1], az = advb[3 * m0 + 2];
        aa0 = ax * ax + ay * ay + az * az;
        float tx = -2.f * ax, ty = -2.f * ay, tz = -2.f * az;
        _Float16 bx = (_Float16)tx, by = (_Float16)ty, bz = (_Float16)tz;
        _Float16 cx = (_Float16)(tx - (float)bx);
        _Float16 cy = (_Float16)(ty - (float)by);
        _Float16 cz = (_Float16)(tz - (float)bz);
        half8 h0 = {bx, by, bz, cx, cy, cz, bx, by};
        half8 h1 = {bz, ONE, ONE, Z, Z, Z, Z, Z};
        bf0 = hk ? h1 : h0;
    }
    {
        float ax = advb[3 * m1], ay = advb[3 * m1 + 1], az = advb[3 * m1 + 2];
        aa1 = ax * ax + ay * ay + az * az;
        float tx = -2.f * ax, ty = -2.f * ay, tz = -2.f * az;
        _Float16 bx = (_Float16)tx, by = (_Float16)ty, bz = (_Float16)tz;
        _Float16 cx = (_Float16)(tx - (float)bx);
        _Float16 cy = (_Float16)(ty - (float)by);
        _Float16 cz = (_Float16)(tz - (float)bz);
        half8 h0 = {bx, by, bz, cx, cy, cz, bx, by};
        half8 h1 = {bz, ONE, ONE, Z, Z, Z, Z, Z};
        bf1 = hk ? h1 : h0;
    }

    f32x16 zc;
#pragma unroll
    for (int i = 0; i < 16; ++i) zc[i] = 0.0f;

    float rm0 = __builtin_huge_valf();
    float rm1 = __builtin_huge_valf();

    const float* orib = ori + (size_t)b * KPTS * 3;
    const int rowbase = ns * RBLK;

    // ---- initial stage: chunk 0 (1 row/thread: load, hi/lo split, 2x b128) ----
    float px, py, pz;
    {
        const float* op = orib + (size_t)(rowbase + tid) * 3;
        px = op[0]; py = op[1]; pz = op[2];
        float oo = px * px + py * py + pz * pz;
        _Float16 hx = (_Float16)px, hy = (_Float16)py, hz = (_Float16)pz;
        _Float16 lx = (_Float16)(px - (float)hx);
        _Float16 ly = (_Float16)(py - (float)hy);
        _Float16 lz = (_Float16)(pz - (float)hz);
        _Float16 oh = (_Float16)oo;
        _Float16 ol = (_Float16)(oo - (float)oh);
        half8 a0 = {hx, hy, hz, hx, hy, hz, lx, ly};
        half8 a1 = {lz, oh, ol, Z, Z, Z, Z, Z};
        *(half8*)(&sA[0][tid * 16])     = a0;
        *(half8*)(&sA[0][tid * 16 + 8]) = a1;
    }
    __syncthreads();

    for (int ch = 0; ch < NCHUNK; ++ch) {
        const int cur = ch & 1;

        // prefetch next chunk's raw rows into registers (latency hides under MFMAs)
        if (ch + 1 < NCHUNK) {
            const float* op = orib + (size_t)(rowbase + (ch + 1) * CHUNK + tid) * 3;
            px = op[0]; py = op[1]; pz = op[2];
        }

        // ---- 8 row-tiles: ds_read_b128 + 2 MFMA + min trees ----
        const _Float16* apl = &sA[cur][r * 16 + hk * 8];
#pragma unroll 4
        for (int t = 0; t < CTILES; ++t) {
            half8 af = *(const half8*)(apl + (size_t)t * (32 * 16));
            f32x16 c0 = __builtin_amdgcn_mfma_f32_32x32x16_f16(af, bf0, zc, 0, 0, 0);
            f32x16 c1 = __builtin_amdgcn_mfma_f32_32x32x16_f16(af, bf1, zc, 0, 0, 0);
            rm0 = fminf(rm0, min16(c0));
            rm1 = fminf(rm1, min16(c1));
        }
        __syncthreads();   // readers of sA[cur^1] (prev chunk) are done

        if (ch + 1 < NCHUNK) {
            float oo = px * px + py * py + pz * pz;
            _Float16 hx = (_Float16)px, hy = (_Float16)py, hz = (_Float16)pz;
            _Float16 lx = (_Float16)(px - (float)hx);
            _Float16 ly = (_Float16)(py - (float)hy);
            _Float16 lz = (_Float16)(pz - (float)hz);
            _Float16 oh = (_Float16)oo;
            _Float16 ol = (_Float16)(oo - (float)oh);
            half8 a0 = {hx, hy, hz, hx, hy, hz, lx, ly};
            half8 a1 = {lz, oh, ol, Z, Z, Z, Z, Z};
            *(half8*)(&sA[cur ^ 1][tid * 16])     = a0;
            *(half8*)(&sA[cur ^ 1][tid * 16 + 8]) = a1;
            __syncthreads();   // next chunk staged
        }
    }

    // complete the 32-row min (lane pair l, l^32 share a column)
    rm0 = fminf(rm0, __shfl_xor(rm0, 32, 64));
    rm1 = fminf(rm1, __shfl_xor(rm1, 32, 64));

    float v0 = fmaxf(rm0 + aa0, 0.0f);
    float v1 = fmaxf(rm1 + aa1, 0.0f);

    // plain coalesced partial-min stores: part[ns][b][col] (no init required)
    float* p = part + ((size_t)ns * BATCH + b) * KPTS;
    if (hk == 0) {
        p[m0] = v0;
        p[m1] = v1;
    }
}

// 8 blocks (one per batch): min over slices, max over columns, weighted add.
__global__ __launch_bounds__(256) void reduceB(const float* __restrict__ part,
                                               const float* __restrict__ w,
                                               float* __restrict__ out) {
    const int b = blockIdx.x;
    const int tid = threadIdx.x;

    float mx = 0.0f;   // partials are clamped nonneg
    for (int m = tid; m < KPTS; m += 256) {
        float mn = part[(size_t)b * KPTS + m];
#pragma unroll
        for (int s = 1; s < NSPLIT; ++s)
            mn = fminf(mn, part[((size_t)s * BATCH + b) * KPTS + m]);
        mx = fmaxf(mx, mn);
    }

#pragma unroll
    for (int off = 32; off; off >>= 1)
        mx = fmaxf(mx, __shfl_xor(mx, off, 64));

    __shared__ float red[4];
    if ((tid & 63) == 0) red[tid >> 6] = mx;
    __syncthreads();
    if (tid == 0) {
        float m2 = fmaxf(fmaxf(red[0], red[1]), fmaxf(red[2], red[3]));
        atomicAdd(out, m2 * w[b] * (1.0f / BATCH));
    }
}

extern "C" void kernel_launch(void* const* d_in, const int* in_sizes, int n_in,
                              void* d_out, int out_size, void* d_ws, size_t ws_size,
                              hipStream_t stream) {
    const float* adv = (const float*)d_in[0];   // [B, K, 3]
    const float* ori = (const float*)d_in[1];   // [B, K, 3]
    const float* w   = (const float*)d_in[2];   // [B]
    float* out = (float*)d_out;
    float* part = (float*)d_ws;                 // NSPLIT*B*K floats = 2 MB

    hausdorff<<<BATCH * 32 * NSPLIT, 256, 0, stream>>>(adv, ori, part, out);
    reduceB<<<BATCH, 256, 0, stream>>>((const float*)part, w, out);
}

// Round 4
// 85.217 us; speedup vs baseline: 1.0575x; 1.0575x over previous
//
#include <hip/hip_runtime.h>

// Hausdorff adv2ori via MFMA: B=8, K=8192.
// dist(n,m) = oo_n + aa_m - 2*o.a ; C = mfma(A',B') = oo_n - 2*o.a (fp16 hi/lo split)
// loss = mean_b( w_b * max_m min_n dist )
//
// K=16 slot packing (one 32x32x16_f16 MFMA per 32x32 pair tile):
//   A'(ori n): [oh.x oh.y oh.z | oh.x oh.y oh.z | ol.x ol.y ol.z | oo_h oo_l | 0 x5]
//   B'(adv m): [bh.x bh.y bh.z | bl.x bl.y bl.z | bh.x bh.y bh.z | 1    1    | 0 x5]
//   b = -2*a; dropped ol.bl terms ~1e-6; fp32 accumulate. absmax=0 in R1-R3.
//
// R3 post-mortem: fixed ~40us harness poison fill dominates top-5; our ~50us =
// hausdorff (LDS-bank-conflicted A-frag ds_read_b128: lanes r,r+4,.. same bank
// quad -> ~4-way, ~15us LDS pipe/CU vs 5.1us floor) + reduceB (8 blocks x 256thr,
// 32 serial HBM-latency rounds ~12us) + gaps.
// R4: (a) K-half-planar LDS tile layout [tile][khalf][row] in 16B granules ->
// lane l reads byte t*1024 + l*16: linear, conflict-free both sides, no swizzle
// math; (b) single barrier per chunk (double-buffer needs only one); (c) reduceB
// 1024 threads, 16 independent float4 loads/thread (one latency round).

#define KPTS 8192
#define BATCH 8

#define CBLK 256              // adv columns per block (4 waves x 64)
#define NSPLIT 8              // row splits, combined via plain-store partials
#define RBLK (KPTS / NSPLIT)  // 1024 ori rows per block
#define CHUNK 256             // rows per LDS buffer (8 KB; x2 double-buffered)
#define NCHUNK (RBLK / CHUNK) // 4
#define CTILES (CHUNK / 32)   // 8 MFMA row-tiles per chunk

typedef _Float16 half8 __attribute__((ext_vector_type(8)));
typedef float f32x16 __attribute__((ext_vector_type(16)));

// min of 16 fp32 (fuses to v_min3 tree)
__device__ __forceinline__ float min16(const f32x16 c) {
    float u0 = fminf(fminf(c[0],  c[1]),  c[2]);
    float u1 = fminf(fminf(c[3],  c[4]),  c[5]);
    float u2 = fminf(fminf(c[6],  c[7]),  c[8]);
    float u3 = fminf(fminf(c[9],  c[10]), c[11]);
    float u4 = fminf(fminf(c[12], c[13]), c[14]);
    float u5 = fminf(fminf(u0, u1), c[15]);
    float u6 = fminf(fminf(u2, u3), u4);
    return fminf(u5, u6);
}

// Convert one ori point to the two A' K-half fragments.
__device__ __forceinline__ void mk_afrag(float x, float y, float z,
                                         half8& a0, half8& a1) {
    const _Float16 Z = (_Float16)0.0f;
    float oo = x * x + y * y + z * z;
    _Float16 hx = (_Float16)x, hy = (_Float16)y, hz = (_Float16)z;
    _Float16 lx = (_Float16)(x - (float)hx);
    _Float16 ly = (_Float16)(y - (float)hy);
    _Float16 lz = (_Float16)(z - (float)hz);
    _Float16 oh = (_Float16)oo;
    _Float16 ol = (_Float16)(oo - (float)oh);
    a0 = half8{hx, hy, hz, hx, hy, hz, lx, ly};
    a1 = half8{lz, oh, ol, Z, Z, Z, Z, Z};
}

__global__ __launch_bounds__(256) void hausdorff(const float* __restrict__ adv,
                                                 const float* __restrict__ ori,
                                                 float* __restrict__ part,
                                                 float* __restrict__ out) {
    // Per 32-row tile: [khalf][row] 16B granules -> 1 KiB/tile, 8 tiles/buffer.
    __shared__ _Float16 sA[2][CHUNK * 16];

    const int bid  = blockIdx.x;             // grid = 8 * 32 * 8 = 2048
    const int b    = bid >> 8;
    const int mc   = (bid >> 3) & 31;        // column chunk (256 cols)
    const int ns   = bid & 7;                // row split
    const int tid  = threadIdx.x;
    const int lane = tid & 63;
    const int wv   = tid >> 6;
    const int r    = lane & 31;              // MFMA row/col index
    const int hk   = lane >> 5;              // K-half

    if (bid == 0 && tid == 0) out[0] = 0.0f; // for reduceB's atomicAdd

    const _Float16 Z = (_Float16)0.0f, ONE = (_Float16)1.0f;

    // ---- B-fragments + aa from adv (once per block, registers) ----
    const float* advb = adv + (size_t)b * KPTS * 3;
    const int m0 = mc * CBLK + wv * 64 + r;
    const int m1 = m0 + 32;
    half8 bf0, bf1;
    float aa0, aa1;
    {
        float ax = advb[3 * m0], ay = advb[3 * m0 + 1], az = advb[3 * m0 + 2];
        aa0 = ax * ax + ay * ay + az * az;
        float tx = -2.f * ax, ty = -2.f * ay, tz = -2.f * az;
        _Float16 bx = (_Float16)tx, by = (_Float16)ty, bz = (_Float16)tz;
        _Float16 cx = (_Float16)(tx - (float)bx);
        _Float16 cy = (_Float16)(ty - (float)by);
        _Float16 cz = (_Float16)(tz - (float)bz);
        half8 h0 = {bx, by, bz, cx, cy, cz, bx, by};
        half8 h1 = {bz, ONE, ONE, Z, Z, Z, Z, Z};
        bf0 = hk ? h1 : h0;
    }
    {
        float ax = advb[3 * m1], ay = advb[3 * m1 + 1], az = advb[3 * m1 + 2];
        aa1 = ax * ax + ay * ay + az * az;
        float tx = -2.f * ax, ty = -2.f * ay, tz = -2.f * az;
        _Float16 bx = (_Float16)tx, by = (_Float16)ty, bz = (_Float16)tz;
        _Float16 cx = (_Float16)(tx - (float)bx);
        _Float16 cy = (_Float16)(ty - (float)by);
        _Float16 cz = (_Float16)(tz - (float)bz);
        half8 h0 = {bx, by, bz, cx, cy, cz, bx, by};
        half8 h1 = {bz, ONE, ONE, Z, Z, Z, Z, Z};
        bf1 = hk ? h1 : h0;
    }

    f32x16 zc;
#pragma unroll
    for (int i = 0; i < 16; ++i) zc[i] = 0.0f;

    float rm0 = __builtin_huge_valf();
    float rm1 = __builtin_huge_valf();

    const float* orib = ori + (size_t)b * KPTS * 3;
    const int rowbase = ns * RBLK;

    // Staging write offsets (halfs): row rr -> tile rr>>5, slot rr&31.
    // khalf0 at (rr>>5)*512 + (rr&31)*8, khalf1 at +256.
    const int woff = ((tid >> 5) << 9) + ((tid & 31) << 3);

    // ---- initial stage: chunk 0 ----
    {
        const float* op = orib + (size_t)(rowbase + tid) * 3;
        half8 a0, a1;
        mk_afrag(op[0], op[1], op[2], a0, a1);
        *(half8*)(&sA[0][woff])       = a0;
        *(half8*)(&sA[0][woff + 256]) = a1;
    }
    __syncthreads();

    // Read offset (halfs): lane*8 within buffer, +512 per tile -> linear 16B/lane.
    const int roff = lane << 3;

    for (int ch = 0; ch < NCHUNK; ++ch) {
        const int cur = ch & 1;

        // prefetch next chunk's raw rows (latency hides under MFMAs)
        float px, py, pz;
        if (ch + 1 < NCHUNK) {
            const float* op = orib + (size_t)(rowbase + (ch + 1) * CHUNK + tid) * 3;
            px = op[0]; py = op[1]; pz = op[2];
        }

        // ---- 8 row-tiles: conflict-free ds_read_b128 + 2 MFMA + min trees ----
        const _Float16* apl = &sA[cur][roff];
#pragma unroll 4
        for (int t = 0; t < CTILES; ++t) {
            half8 af = *(const half8*)(apl + (size_t)t * 512);
            f32x16 c0 = __builtin_amdgcn_mfma_f32_32x32x16_f16(af, bf0, zc, 0, 0, 0);
            f32x16 c1 = __builtin_amdgcn_mfma_f32_32x32x16_f16(af, bf1, zc, 0, 0, 0);
            rm0 = fminf(rm0, min16(c0));
            rm1 = fminf(rm1, min16(c1));
        }

        // stage next chunk (write to the idle buffer; one barrier per chunk)
        if (ch + 1 < NCHUNK) {
            half8 a0, a1;
            mk_afrag(px, py, pz, a0, a1);
            *(half8*)(&sA[cur ^ 1][woff])       = a0;
            *(half8*)(&sA[cur ^ 1][woff + 256]) = a1;
            __syncthreads();
        }
    }

    // complete the 32-row min (lane pair l, l^32 share a column)
    rm0 = fminf(rm0, __shfl_xor(rm0, 32, 64));
    rm1 = fminf(rm1, __shfl_xor(rm1, 32, 64));

    float v0 = fmaxf(rm0 + aa0, 0.0f);
    float v1 = fmaxf(rm1 + aa1, 0.0f);

    // plain coalesced partial-min stores: part[ns][b][col] (no init required)
    float* p = part + ((size_t)ns * BATCH + b) * KPTS;
    if (hk == 0) {
        p[m0] = v0;
        p[m1] = v1;
    }
}

// 8 blocks (one per batch), 1024 threads: min over slices, max over columns.
// All 16 float4 loads per thread are independent -> single latency round.
__global__ __launch_bounds__(1024) void reduceB(const float* __restrict__ part,
                                                const float* __restrict__ w,
                                                float* __restrict__ out) {
    const int b = blockIdx.x;
    const int tid = threadIdx.x;

    float mx = 0.0f;   // partials are clamped nonneg
#pragma unroll
    for (int h = 0; h < 2; ++h) {
        const int c4 = tid + h * 1024;       // float4 index, 2048 per row
        float4 v[NSPLIT];
#pragma unroll
        for (int s = 0; s < NSPLIT; ++s)
            v[s] = *(const float4*)(part + ((size_t)s * BATCH + b) * KPTS + (size_t)c4 * 4);
        float4 mn = v[0];
#pragma unroll
        for (int s = 1; s < NSPLIT; ++s) {
            mn.x = fminf(mn.x, v[s].x); mn.y = fminf(mn.y, v[s].y);
            mn.z = fminf(mn.z, v[s].z); mn.w = fminf(mn.w, v[s].w);
        }
        mx = fmaxf(mx, fmaxf(fmaxf(mn.x, mn.y), fmaxf(mn.z, mn.w)));
    }

#pragma unroll
    for (int off = 32; off; off >>= 1)
        mx = fmaxf(mx, __shfl_xor(mx, off, 64));

    __shared__ float red[16];
    if ((tid & 63) == 0) red[tid >> 6] = mx;
    __syncthreads();
    if (tid == 0) {
        float m2 = red[0];
#pragma unroll
        for (int i = 1; i < 16; ++i) m2 = fmaxf(m2, red[i]);
        atomicAdd(out, m2 * w[b] * (1.0f / BATCH));
    }
}

extern "C" void kernel_launch(void* const* d_in, const int* in_sizes, int n_in,
                              void* d_out, int out_size, void* d_ws, size_t ws_size,
                              hipStream_t stream) {
    const float* adv = (const float*)d_in[0];   // [B, K, 3]
    const float* ori = (const float*)d_in[1];   // [B, K, 3]
    const float* w   = (const float*)d_in[2];   // [B]
    float* out = (float*)d_out;
    float* part = (float*)d_ws;                 // NSPLIT*B*K floats = 2 MB

    hausdorff<<<BATCH * 32 * NSPLIT, 256, 0, stream>>>(adv, ori, part, out);
    reduceB<<<BATCH, 1024, 0, stream>>>((const float*)part, w, out);
}